// Round 10
// baseline (164.871 us; speedup 1.0000x reference)
//
#include <hip/hip_runtime.h>
#include <hip/hip_bf16.h>
#include <math.h>

constexpr int B_  = 16;
constexpr int C_  = 1536;
constexpr int T_  = 2000;
constexpr int H_  = 128;
constexpr int C3_ = 3 * C_;   // 4608
constexpr int C2_ = 2 * C_;   // 3072
constexpr int NT_ = 4;        // t-parts for gemm2; 12*16*4 = 768 = 3 blocks/CU
constexpr int NTL_ = 32;      // gemm1 t-tiles (64 t each)

typedef short bf8 __attribute__((ext_vector_type(8)));   // 8 bf16 (4 VGPR) MFMA A/B frag
typedef short bf4 __attribute__((ext_vector_type(4)));   // 4 bf16 (8B)
typedef float f4  __attribute__((ext_vector_type(4)));   // MFMA C/D frag

// fp32 -> bf16 RTNE via HARDWARE cvt (compiler pairs casts into
// v_cvt_pk_bf16_f32). R9's bit-twiddle version was ~5 VALU ops/element and
// made the gemm1 staging loop VALU-bound. Same rounding -> identical bits.
__device__ inline unsigned short f2b(float f) {
  __bf16 h = (__bf16)f;
  return __builtin_bit_cast(unsigned short, h);
}

// ---------------- K1: MFMA GEMM1 main loop + FUSED masked-stats partials ------
// block 256 thr (4 waves), tile 128h x 64t; wave w owns t-slice w*16..+15.
// Writes h_pre[b][t][h] fp32 (raw GEMM acc) and per-(c, t-tile) partial
// sums sp1 = sum_t m*x, sp2 = sum_t m*x*x (each x element staged exactly once).
__global__ __launch_bounds__(256) void k_gemm1_stats(
    const float* __restrict__ x, const float* __restrict__ w1,
    const float* __restrict__ mask,
    float* __restrict__ h_pre, float* __restrict__ sp1, float* __restrict__ sp2) {
  __shared__ __align__(16) short As[2][128 * 32];
  __shared__ __align__(16) short Bs[2][64 * 32];
  const int b = blockIdx.y;
  const int tile = blockIdx.x;
  const int t0 = tile * 64;
  const int tid = threadIdx.x;
  const int lane = tid & 63;
  const int w = tid >> 6;
  const int l15 = lane & 15;
  const int l4 = lane >> 4;

  float4 va[4], vb[2];

  // mask regs for this thread's fixed 4 t-columns (t4 = tid&15, q-invariant)
  const int t4 = tid & 15;
  float mreg[4];
#pragma unroll
  for (int j = 0; j < 4; ++j) {
    int t = t0 + t4 * 4 + j;
    mreg[j] = (t < T_) ? mask[(size_t)b * T_ + t] : 0.f;
  }
  float* sp1row = sp1 + ((size_t)b * NTL_ + tile) * C_;
  float* sp2row = sp2 + ((size_t)b * NTL_ + tile) * C_;

  f4 acc[8];
#pragma unroll
  for (int mi = 0; mi < 8; ++mi) { f4 z = {0.f, 0.f, 0.f, 0.f}; acc[mi] = z; }

#define G1_GLOAD(K0)                                                          \
  {                                                                           \
    _Pragma("unroll")                                                         \
    for (int q = 0; q < 4; ++q) {                                             \
      int idx = q * 256 + tid;                                                \
      int row = idx >> 3, j4 = idx & 7;                                       \
      va[q] = *(const float4*)(w1 + (size_t)row * C3_ + (K0) + j4 * 4);       \
    }                                                                         \
    _Pragma("unroll")                                                         \
    for (int q = 0; q < 2; ++q) {                                             \
      int idx = q * 256 + tid;                                                \
      int k = idx >> 4;                                                       \
      int t = t0 + t4 * 4;                                                    \
      if (t < T_)                                                             \
        vb[q] = *(const float4*)(x + ((size_t)(b * C_ + (K0) + k)) * T_ + t); \
      else                                                                    \
        vb[q] = make_float4(0.f, 0.f, 0.f, 0.f);                              \
    }                                                                         \
  }
#define G1_LSTORE(BUF)                                                        \
  {                                                                           \
    _Pragma("unroll")                                                         \
    for (int q = 0; q < 4; ++q) {                                             \
      int idx = q * 256 + tid;                                                \
      int row = idx >> 3, j4 = idx & 7;                                       \
      int slot = (j4 >> 1) ^ ((row >> 2) & 3);                                \
      bf4 p;                                                                  \
      p[0] = (short)f2b(va[q].x); p[1] = (short)f2b(va[q].y);                 \
      p[2] = (short)f2b(va[q].z); p[3] = (short)f2b(va[q].w);                 \
      *(bf4*)&As[BUF][row * 32 + slot * 8 + (j4 & 1) * 4] = p;                \
    }                                                                         \
    _Pragma("unroll")                                                         \
    for (int q = 0; q < 2; ++q) {                                             \
      int idx = q * 256 + tid;                                                \
      int k = idx >> 4;                                                       \
      float vv[4] = {vb[q].x, vb[q].y, vb[q].z, vb[q].w};                     \
      _Pragma("unroll")                                                       \
      for (int j = 0; j < 4; ++j) {                                           \
        int row = t4 * 4 + j;                                                 \
        int slot = (k >> 3) ^ ((row >> 2) & 3);                               \
        Bs[BUF][row * 32 + slot * 8 + (k & 7)] = (short)f2b(vv[j]);           \
      }                                                                       \
    }                                                                         \
  }
// stats partials for the k-tile just loaded into vb; reduce over the 16
// lanes sharing a k-row (consecutive tid), leader writes (c unique per block)
#define G1_STATS(K0)                                                          \
  {                                                                           \
    _Pragma("unroll")                                                         \
    for (int q = 0; q < 2; ++q) {                                             \
      float vv[4] = {vb[q].x, vb[q].y, vb[q].z, vb[q].w};                     \
      float a1 = 0.f, a2 = 0.f;                                               \
      _Pragma("unroll")                                                       \
      for (int j = 0; j < 4; ++j) {                                           \
        float mx = mreg[j] * vv[j];                                           \
        a1 += mx;                                                             \
        a2 = fmaf(mx, vv[j], a2);                                             \
      }                                                                       \
      _Pragma("unroll")                                                       \
      for (int off = 1; off < 16; off <<= 1) {                                \
        a1 += __shfl_xor(a1, off);                                            \
        a2 += __shfl_xor(a2, off);                                            \
      }                                                                       \
      if (t4 == 0) {                                                          \
        int c = (K0) + q * 16 + (tid >> 4);                                   \
        sp1row[c] = a1;                                                       \
        sp2row[c] = a2;                                                       \
      }                                                                       \
    }                                                                         \
  }

  G1_GLOAD(0);
  G1_LSTORE(0);
  G1_STATS(0);
  __syncthreads();

  const int fA = (l15 >> 2) & 3;        // row-swizzle term, mi/w-independent
  const int NS = C_ / 32;               // 48 K-steps
  for (int s = 0; s < NS; ++s) {
    const int cur = s & 1;
    if (s + 1 < NS) G1_GLOAD((s + 1) * 32);
    {
      const int browB = w * 16 + l15;
      bf8 bfr = *(const bf8*)&Bs[cur][browB * 32 + (l4 ^ fA) * 8];
#pragma unroll
      for (int mi = 0; mi < 8; ++mi) {
        bf8 afr = *(const bf8*)&As[cur][(mi * 16 + l15) * 32 + (l4 ^ fA) * 8];
        acc[mi] = __builtin_amdgcn_mfma_f32_16x16x32_bf16(afr, bfr, acc[mi], 0, 0, 0);
      }
    }
    if (s + 1 < NS) {
      G1_LSTORE(cur ^ 1);
      G1_STATS((s + 1) * 32);
    }
    __syncthreads();
  }

  // store raw acc (pre-hconst/relu/LN) as fp32 h_pre[b][t][h]
  const int t = t0 + w * 16 + l15;
  if (t < T_) {
    float* dst = h_pre + ((size_t)b * T_ + t) * H_;
#pragma unroll
    for (int mi = 0; mi < 8; ++mi)
      *(f4*)&dst[mi * 16 + l4 * 4] = acc[mi];
  }
}

// ---------------- K2: reduce stats partials -> mean0/std0 ---------------------
__global__ __launch_bounds__(256) void k_stats_reduce(
    const float* __restrict__ sp1, const float* __restrict__ sp2,
    const float* __restrict__ mask,
    float* __restrict__ mean0, float* __restrict__ std0) {
  __shared__ float rs[4];
  const int b = blockIdx.x / (C_ / 256);
  const int chunk = blockIdx.x % (C_ / 256);
  const int tid = threadIdx.x;
  const int lane = tid & 63;
  const int wv = tid >> 6;
  // block-wide sum of mask row
  float sm = 0.f;
  for (int i = tid; i < T_; i += 256) sm += mask[(size_t)b * T_ + i];
#pragma unroll
  for (int off = 32; off; off >>= 1) sm += __shfl_xor(sm, off);
  if (lane == 0) rs[wv] = sm;
  __syncthreads();
  sm = rs[0] + rs[1] + rs[2] + rs[3];

  const int c = chunk * 256 + tid;
  float s1 = 0.f, s2 = 0.f;
#pragma unroll 8
  for (int tile = 0; tile < NTL_; ++tile) {
    const size_t j = ((size_t)b * NTL_ + tile) * C_ + c;
    s1 += sp1[j];
    s2 += sp2[j];
  }
  float mean = s1 / sm;
  float var = s2 / sm - mean * mean;
  mean0[b * C_ + c] = mean;
  std0[b * C_ + c] = sqrtf(fmaxf(var, 1e-5f));
}

// ---------------- K3: hconst GEMV + wl1 L1-norms in ONE launch ----------------
__global__ __launch_bounds__(256) void k_hconst_wl1(
    const float* __restrict__ w1, const float* __restrict__ b1,
    const float* __restrict__ mean0, const float* __restrict__ std0,
    const float* __restrict__ w2,
    float* __restrict__ hconst, float* __restrict__ wl1) {
  const int wave = threadIdx.x >> 6;
  const int lane = threadIdx.x & 63;
  if (blockIdx.x < B_ * H_ / 4) {
    const int idx = blockIdx.x * 4 + wave;      // b*H + h
    const int b = idx >> 7;
    const int h = idx & (H_ - 1);
    const float* wm  = w1 + (size_t)h * C3_ + C_;
    const float* wsd = wm + C_;
    const float* mn = mean0 + b * C_;
    const float* sd = std0 + b * C_;
    float s = 0.f;
    for (int c = lane; c < C_; c += 64)
      s += wm[c] * mn[c] + wsd[c] * sd[c];
#pragma unroll
    for (int off = 32; off; off >>= 1) s += __shfl_xor(s, off);
    if (lane == 0) hconst[idx] = s + b1[h];
  } else {
    const int c = (blockIdx.x - B_ * H_ / 4) * 4 + wave;
    const float* wr = w2 + (size_t)c * H_;
    float s = fabsf(wr[lane]) + fabsf(wr[lane + 64]);
#pragma unroll
    for (int off = 32; off; off >>= 1) s += __shfl_xor(s, off);
    if (lane == 0) wl1[c] = s;
  }
}

// ---------------- K4: LN epilogue: h_pre + hconst -> relu -> LN(H) -> tanh ----
// grid (32 t-tiles, B); 256 thr = 64 t x 4 parts; part owns 32 h of one t.
__global__ __launch_bounds__(256) void k_ln_epi(
    const float* __restrict__ h_pre, const float* __restrict__ hconst,
    const float* __restrict__ g1, const float* __restrict__ be1,
    unsigned short* __restrict__ hlnT) {
  const int b = blockIdx.y;
  const int t = blockIdx.x * 64 + (threadIdx.x >> 2);
  const int part = threadIdx.x & 3;
  if (t >= T_) return;
  const float* src = h_pre + ((size_t)b * T_ + t) * H_ + part * 32;
  const float* hc = hconst + b * H_ + part * 32;
  float v[32];
  float sum = 0.f, ssq = 0.f;
#pragma unroll
  for (int j = 0; j < 8; ++j) {
    float4 h4 = *(const float4*)(src + j * 4);
    float4 c4 = *(const float4*)(hc + j * 4);
    const float* hp = (const float*)&h4;
    const float* cp = (const float*)&c4;
#pragma unroll
    for (int r = 0; r < 4; ++r) {
      float u = fmaxf(hp[r] + cp[r], 0.f);
      v[j * 4 + r] = u;
      sum += u;
      ssq += u * u;
    }
  }
  // reduce over the 4 parts (consecutive lanes)
  sum += __shfl_xor(sum, 1); sum += __shfl_xor(sum, 2);
  ssq += __shfl_xor(ssq, 1); ssq += __shfl_xor(ssq, 2);
  const float mean = sum * (1.f / 128.f);
  const float rstd = rsqrtf(ssq * (1.f / 128.f) - mean * mean + 1e-5f);
  unsigned short* dst = hlnT + ((size_t)b * T_ + t) * H_ + part * 32;
  const float* gp = g1 + part * 32;
  const float* ep = be1 + part * 32;
#pragma unroll
  for (int m = 0; m < 4; ++m) {
    bf8 p;
#pragma unroll
    for (int r = 0; r < 8; ++r) {
      int j = m * 8 + r;
      p[r] = (short)f2b(tanhf((v[j] - mean) * rstd * gp[j] + ep[j]));
    }
    *(bf8*)&dst[m * 8] = p;
  }
}

// ---------------- K5: MFMA GEMM2 (alpha=w2@hln) + FIXED-MAX softmax + pooling -
// grid (12 c-tiles, B, NT parts); part owns t in [part*512, min(+512,T)).
// A-operand (w2 rows) in REGISTERS (L2-resident); LDS = Hs 32KB only.
// Plain launch_bounds: R7's (256,3) min-waves forced scratch spills.
// e = exp(alpha - wl1[c]): no running max, no rescale; Mc cancels in s1/s0.
__global__ __launch_bounds__(256) void k_gemm2_pool(
    const float* __restrict__ x, const float* __restrict__ mask,
    const float* __restrict__ w2, const unsigned short* __restrict__ hlnT,
    const float* __restrict__ wl1,
    float* __restrict__ ps0, float* __restrict__ ps1, float* __restrict__ ps2) {
  __shared__ __align__(16) short Hs[2][64 * 128];   // [t][h] swizzled, 2x16KB
  const int b = blockIdx.y;
  const int c0 = blockIdx.x * 128;
  const int part = blockIdx.z;
  const int tb = part * 512;
  const int te = min(tb + 512, T_);
  const int tid = threadIdx.x;
  const int lane = tid & 63;
  const int w = tid >> 6;
  const int l15 = lane & 15;
  const int l4 = lane >> 4;

  // A-frags in registers: af[mi][ks] = w2[c0+w*32+mi*16+l15][(ks*4+l4)*8 ..+8]
  bf8 af[2][4];
#pragma unroll
  for (int mi = 0; mi < 2; ++mi)
#pragma unroll
    for (int ks = 0; ks < 4; ++ks) {
      const float* src = w2 + (size_t)(c0 + w * 32 + mi * 16 + l15) * H_ + (ks * 4 + l4) * 8;
      float4 v0 = *(const float4*)src;
      float4 v1 = *(const float4*)(src + 4);
      bf8 p;
      p[0] = (short)f2b(v0.x); p[1] = (short)f2b(v0.y);
      p[2] = (short)f2b(v0.z); p[3] = (short)f2b(v0.w);
      p[4] = (short)f2b(v1.x); p[5] = (short)f2b(v1.y);
      p[6] = (short)f2b(v1.z); p[7] = (short)f2b(v1.w);
      af[mi][ks] = p;
    }

  // static per-row logit bound Mc (exp arg <= 0, never overflows)
  float Mc[8];
#pragma unroll
  for (int mi = 0; mi < 2; ++mi) {
    float4 m4 = *(const float4*)(wl1 + c0 + w * 32 + mi * 16 + l4 * 4);
    Mc[mi * 4 + 0] = m4.x; Mc[mi * 4 + 1] = m4.y;
    Mc[mi * 4 + 2] = m4.z; Mc[mi * 4 + 3] = m4.w;
  }

  float s0[8], s1[8], s2[8];
#pragma unroll
  for (int r = 0; r < 8; ++r) { s0[r] = 0.f; s1[r] = 0.f; s2[r] = 0.f; }

  bf8 hreg[4];
#define G2_HLOAD(T0)                                                          \
  {                                                                           \
    _Pragma("unroll")                                                         \
    for (int q = 0; q < 4; ++q) {                                             \
      int idx = q * 256 + tid;                                                \
      int row = idx >> 4, slot = idx & 15;                                    \
      int t = (T0) + row;                                                     \
      if (t > T_ - 1) t = T_ - 1;                                             \
      hreg[q] = *(const bf8*)(hlnT + ((size_t)b * T_ + t) * H_ + slot * 8);   \
    }                                                                         \
  }
#define G2_HSTORE(BUF)                                                        \
  {                                                                           \
    _Pragma("unroll")                                                         \
    for (int q = 0; q < 4; ++q) {                                             \
      int idx = q * 256 + tid;                                                \
      int row = idx >> 4, slot = idx & 15;                                    \
      *(bf8*)&Hs[BUF][row * 128 + (slot ^ (row & 15)) * 8] = hreg[q];         \
    }                                                                         \
  }

  G2_HLOAD(tb);
  G2_HSTORE(0);
  __syncthreads();

  const int NCH = (te - tb + 63) / 64;   // <= 8
  for (int ch = 0; ch < NCH; ++ch) {
    const int t0 = tb + ch * 64;
    const int cur = ch & 1;
    if (ch + 1 < NCH) G2_HLOAD(t0 + 64);

    // issue-early: mask + x loads for this chunk, consumed after MFMA
    float mk[4];
    int tcol[4];
#pragma unroll
    for (int nj = 0; nj < 4; ++nj) {
      int t = t0 + nj * 16 + l15;
      tcol[nj] = (t < T_) ? t : (T_ - 1);
      mk[nj] = (t < T_) ? mask[(size_t)b * T_ + t] : 0.f;
    }
    float xv[8][4];
#pragma unroll
    for (int mi = 0; mi < 2; ++mi)
#pragma unroll
      for (int reg = 0; reg < 4; ++reg) {
        const int c = c0 + w * 32 + mi * 16 + l4 * 4 + reg;
        const float* xrow = x + ((size_t)(b * C_ + c)) * T_;
#pragma unroll
        for (int nj = 0; nj < 4; ++nj) xv[mi * 4 + reg][nj] = xrow[tcol[nj]];
      }

    f4 acc[2][4];
#pragma unroll
    for (int mi = 0; mi < 2; ++mi)
#pragma unroll
      for (int nj = 0; nj < 4; ++nj) { f4 z = {0.f, 0.f, 0.f, 0.f}; acc[mi][nj] = z; }

#pragma unroll
    for (int ks = 0; ks < 4; ++ks) {
      const int sw = (ks * 4 + l4) ^ l15;   // row&15 == l15 for B rows
      bf8 bb[4];
#pragma unroll
      for (int nj = 0; nj < 4; ++nj)
        bb[nj] = *(const bf8*)&Hs[cur][(nj * 16 + l15) * 128 + sw * 8];
#pragma unroll
      for (int nj = 0; nj < 4; ++nj) {
        acc[0][nj] = __builtin_amdgcn_mfma_f32_16x16x32_bf16(af[0][ks], bb[nj], acc[0][nj], 0, 0, 0);
        acc[1][nj] = __builtin_amdgcn_mfma_f32_16x16x32_bf16(af[1][ks], bb[nj], acc[1][nj], 0, 0, 0);
      }
    }

    // epilogue: fixed-max exp + pooled partial sums (no serial chain)
#pragma unroll
    for (int mi = 0; mi < 2; ++mi)
#pragma unroll
      for (int reg = 0; reg < 4; ++reg) {
        const int r = mi * 4 + reg;
        float a0 = s0[r], a1 = s1[r], a2 = s2[r];
#pragma unroll
        for (int nj = 0; nj < 4; ++nj) {
          float e = (mk[nj] != 0.f) ? __expf(acc[mi][nj][reg] - Mc[r]) : 0.f;
          float xvv = xv[r][nj];
          a0 += e; a1 += e * xvv; a2 += e * xvv * xvv;
        }
        s0[r] = a0; s1[r] = a1; s2[r] = a2;
      }

    // HSTORE after the epilogue: the epilogue VALU hides this iter's HLOAD
    // latency; buffer cur^1 was drained at the previous iteration's barrier.
    if (ch + 1 < NCH) G2_HSTORE(cur ^ 1);
    __syncthreads();
  }

  // merge the 16 lanes (t-cols) of each row group: plain adds
#pragma unroll
  for (int off = 1; off < 16; off <<= 1) {
#pragma unroll
    for (int r = 0; r < 8; ++r) {
      s0[r] += __shfl_xor(s0[r], off);
      s1[r] += __shfl_xor(s1[r], off);
      s2[r] += __shfl_xor(s2[r], off);
    }
  }
  if (l15 == 0) {
#pragma unroll
    for (int mi = 0; mi < 2; ++mi)
#pragma unroll
      for (int reg = 0; reg < 4; ++reg) {
        const int r = mi * 4 + reg;
        const int c = c0 + w * 32 + mi * 16 + l4 * 4 + reg;
        const size_t j = ((size_t)(b * NT_ + part)) * C_ + c;
        ps0[j] = s0[r]; ps1[j] = s1[r]; ps2[j] = s2[r];
      }
  }
}

// ---------------- K5b: plain-sum the NT t-part partials -> pooled -------------
__global__ __launch_bounds__(256) void k_pool_merge(
    const float* __restrict__ ps0, const float* __restrict__ ps1,
    const float* __restrict__ ps2, float* __restrict__ pooled) {
  const int idx = blockIdx.x * 256 + threadIdx.x;   // b*C + c
  const int b = idx / C_;
  const int c = idx - b * C_;
  float s0 = 0.f, s1 = 0.f, s2 = 0.f;
#pragma unroll
  for (int p = 0; p < NT_; ++p) {
    const size_t j = ((size_t)(b * NT_ + p)) * C_ + c;
    s0 += ps0[j]; s1 += ps1[j]; s2 += ps2[j];
  }
  float mean = s1 / s0;
  float var = s2 / s0 - mean * mean;
  pooled[b * C2_ + c] = mean;
  pooled[b * C2_ + C_ + c] = sqrtf(fmaxf(var, 1e-5f));
}

// ---------------- K6: final LN over 2C channels per b -------------------------
__global__ __launch_bounds__(256) void k_final_ln(
    const float* __restrict__ pooled, const float* __restrict__ g2,
    const float* __restrict__ be2, float* __restrict__ out) {
  __shared__ float rs[8];
  const int b = blockIdx.x;
  const int tid = threadIdx.x;
  const int lane = tid & 63;
  const int wave = tid >> 6;
  const float* p = pooled + b * C2_;
  float s = 0.f, q = 0.f;
  for (int i = tid; i < C2_; i += 256) {
    float v = p[i];
    s += v;
    q += v * v;
  }
#pragma unroll
  for (int off = 32; off; off >>= 1) {
    s += __shfl_xor(s, off);
    q += __shfl_xor(q, off);
  }
  if (lane == 0) { rs[wave] = s; rs[4 + wave] = q; }
  __syncthreads();
  s = rs[0] + rs[1] + rs[2] + rs[3];
  q = rs[4] + rs[5] + rs[6] + rs[7];
  float mean = s * (1.f / C2_);
  float var = q * (1.f / C2_) - mean * mean;
  float rstd = rsqrtf(var + 1e-5f);
  for (int i = tid; i < C2_; i += 256)
    out[b * C2_ + i] = (p[i] - mean) * rstd * g2[i] + be2[i];
}

extern "C" void kernel_launch(void* const* d_in, const int* in_sizes, int n_in,
                              void* d_out, int out_size, void* d_ws, size_t ws_size,
                              hipStream_t stream) {
  const float* x    = (const float*)d_in[0];
  const float* mask = (const float*)d_in[1];
  const float* w1   = (const float*)d_in[2];
  const float* b1   = (const float*)d_in[3];
  const float* g1   = (const float*)d_in[4];
  const float* be1  = (const float*)d_in[5];
  const float* w2   = (const float*)d_in[6];
  // d_in[7] = b2: per-(b,c) constant on softmax logits -> softmax-invariant, dropped
  const float* g2   = (const float*)d_in[8];
  const float* be2  = (const float*)d_in[9];
  float* out = (float*)d_out;

  float* ws     = (float*)d_ws;
  float* mean0  = ws;                   // B*C
  float* std0   = mean0 + B_ * C_;      // B*C
  float* hconst = std0 + B_ * C_;       // B*H
  float* pooled = hconst + B_ * H_;     // B*2C
  float* wl1    = pooled + B_ * C2_;    // C
  float* ps0    = wl1 + C_;             // B*NT*C each:
  float* ps1    = ps0 + B_ * NT_ * C_;
  float* ps2    = ps1 + B_ * NT_ * C_;
  float* sp1    = ps2 + B_ * NT_ * C_;  // B*NTL*C each:
  float* sp2    = sp1 + B_ * NTL_ * C_;
  float* h_pre  = sp2 + B_ * NTL_ * C_; // B*T*H fp32, 16.4MB
  unsigned short* hlnT = (unsigned short*)(h_pre + (size_t)B_ * T_ * H_);  // B*T*H bf16

  k_gemm1_stats<<<dim3(NTL_, B_), dim3(256), 0, stream>>>(x, w1, mask, h_pre, sp1, sp2);
  k_stats_reduce<<<dim3(B_ * C_ / 256), dim3(256), 0, stream>>>(sp1, sp2, mask, mean0, std0);
  k_hconst_wl1<<<dim3(B_ * H_ / 4 + C_ / 4), dim3(256), 0, stream>>>(
      w1, b1, mean0, std0, w2, hconst, wl1);
  k_ln_epi<<<dim3(NTL_, B_), dim3(256), 0, stream>>>(h_pre, hconst, g1, be1, hlnT);
  k_gemm2_pool<<<dim3(C_ / 128, B_, NT_), dim3(256), 0, stream>>>(x, mask, w2, hlnT, wl1,
                                                                  ps0, ps1, ps2);
  k_pool_merge<<<dim3(B_ * C_ / 256), dim3(256), 0, stream>>>(ps0, ps1, ps2, pooled);
  k_final_ln<<<dim3(B_), dim3(256), 0, stream>>>(pooled, g2, be2, out);
}

// Round 11
// 161.243 us; speedup vs baseline: 1.0225x; 1.0225x over previous
//
#include <hip/hip_runtime.h>
#include <hip/hip_bf16.h>
#include <math.h>

constexpr int B_  = 16;
constexpr int C_  = 1536;
constexpr int T_  = 2000;
constexpr int H_  = 128;
constexpr int C3_ = 3 * C_;   // 4608
constexpr int C2_ = 2 * C_;   // 3072
constexpr int NT_ = 4;        // t-parts for gemm2 (512 t each)
constexpr int NTL_ = 32;      // gemm1 t-tiles (64 t each)
constexpr int KH_ = C_ / 2;   // gemm1 K-half (768)

typedef short bf8 __attribute__((ext_vector_type(8)));   // 8 bf16 (4 VGPR) MFMA A/B frag
typedef short bf4 __attribute__((ext_vector_type(4)));   // 4 bf16 (8B)
typedef float f4  __attribute__((ext_vector_type(4)));   // MFMA C/D frag

// fp32 -> bf16 RTNE (hardware cvt; compiler pairs into v_cvt_pk_bf16_f32)
__device__ inline unsigned short f2b(float f) {
  __bf16 h = (__bf16)f;
  return __builtin_bit_cast(unsigned short, h);
}

// ---------------- K1: MFMA GEMM1 (K-split x2) + FUSED masked-stats partials ---
// grid (32 t-tiles, B, 2 K-halves); block 256 thr (4 waves), tile 128h x 64t,
// K-range [z*768, +768). Writes h_pre[z][b][t][h] fp32 partial acc and
// per-(c, t-tile) stats partials (the staged k-range IS the stats c-range,
// so the two K-half blocks write disjoint c of the same sp rows).
__global__ __launch_bounds__(256) void k_gemm1_stats(
    const float* __restrict__ x, const float* __restrict__ w1,
    const float* __restrict__ mask,
    float* __restrict__ h_pre, float* __restrict__ sp1, float* __restrict__ sp2) {
  __shared__ __align__(16) short As[2][128 * 32];
  __shared__ __align__(16) short Bs[2][64 * 32];
  const int b = blockIdx.y;
  const int tile = blockIdx.x;
  const int kbase = blockIdx.z * KH_;
  const int t0 = tile * 64;
  const int tid = threadIdx.x;
  const int lane = tid & 63;
  const int w = tid >> 6;
  const int l15 = lane & 15;
  const int l4 = lane >> 4;

  float4 va[4], vb[2];

  // mask regs for this thread's fixed 4 t-columns (t4 = tid&15, q-invariant)
  const int t4 = tid & 15;
  float mreg[4];
#pragma unroll
  for (int j = 0; j < 4; ++j) {
    int t = t0 + t4 * 4 + j;
    mreg[j] = (t < T_) ? mask[(size_t)b * T_ + t] : 0.f;
  }
  float* sp1row = sp1 + ((size_t)b * NTL_ + tile) * C_;
  float* sp2row = sp2 + ((size_t)b * NTL_ + tile) * C_;

  f4 acc[8];
#pragma unroll
  for (int mi = 0; mi < 8; ++mi) { f4 z = {0.f, 0.f, 0.f, 0.f}; acc[mi] = z; }

#define G1_GLOAD(K0)                                                          \
  {                                                                           \
    _Pragma("unroll")                                                         \
    for (int q = 0; q < 4; ++q) {                                             \
      int idx = q * 256 + tid;                                                \
      int row = idx >> 3, j4 = idx & 7;                                       \
      va[q] = *(const float4*)(w1 + (size_t)row * C3_ + (K0) + j4 * 4);       \
    }                                                                         \
    _Pragma("unroll")                                                         \
    for (int q = 0; q < 2; ++q) {                                             \
      int idx = q * 256 + tid;                                                \
      int k = idx >> 4;                                                       \
      int t = t0 + t4 * 4;                                                    \
      if (t < T_)                                                             \
        vb[q] = *(const float4*)(x + ((size_t)(b * C_ + (K0) + k)) * T_ + t); \
      else                                                                    \
        vb[q] = make_float4(0.f, 0.f, 0.f, 0.f);                              \
    }                                                                         \
  }
#define G1_LSTORE(BUF)                                                        \
  {                                                                           \
    _Pragma("unroll")                                                         \
    for (int q = 0; q < 4; ++q) {                                             \
      int idx = q * 256 + tid;                                                \
      int row = idx >> 3, j4 = idx & 7;                                       \
      int slot = (j4 >> 1) ^ ((row >> 2) & 3);                                \
      bf4 p;                                                                  \
      p[0] = (short)f2b(va[q].x); p[1] = (short)f2b(va[q].y);                 \
      p[2] = (short)f2b(va[q].z); p[3] = (short)f2b(va[q].w);                 \
      *(bf4*)&As[BUF][row * 32 + slot * 8 + (j4 & 1) * 4] = p;                \
    }                                                                         \
    _Pragma("unroll")                                                         \
    for (int q = 0; q < 2; ++q) {                                             \
      int idx = q * 256 + tid;                                                \
      int k = idx >> 4;                                                       \
      float vv[4] = {vb[q].x, vb[q].y, vb[q].z, vb[q].w};                     \
      _Pragma("unroll")                                                       \
      for (int j = 0; j < 4; ++j) {                                           \
        int row = t4 * 4 + j;                                                 \
        int slot = (k >> 3) ^ ((row >> 2) & 3);                               \
        Bs[BUF][row * 32 + slot * 8 + (k & 7)] = (short)f2b(vv[j]);           \
      }                                                                       \
    }                                                                         \
  }
// stats partials for the k-tile just loaded into vb; reduce over the 16
// lanes sharing a k-row (consecutive tid), leader writes (c unique per block)
#define G1_STATS(K0)                                                          \
  {                                                                           \
    _Pragma("unroll")                                                         \
    for (int q = 0; q < 2; ++q) {                                             \
      float vv[4] = {vb[q].x, vb[q].y, vb[q].z, vb[q].w};                     \
      float a1 = 0.f, a2 = 0.f;                                               \
      _Pragma("unroll")                                                       \
      for (int j = 0; j < 4; ++j) {                                           \
        float mx = mreg[j] * vv[j];                                           \
        a1 += mx;                                                             \
        a2 = fmaf(mx, vv[j], a2);                                             \
      }                                                                       \
      _Pragma("unroll")                                                       \
      for (int off = 1; off < 16; off <<= 1) {                                \
        a1 += __shfl_xor(a1, off);                                            \
        a2 += __shfl_xor(a2, off);                                            \
      }                                                                       \
      if (t4 == 0) {                                                          \
        int c = (K0) + q * 16 + (tid >> 4);                                   \
        sp1row[c] = a1;                                                       \
        sp2row[c] = a2;                                                       \
      }                                                                       \
    }                                                                         \
  }

  G1_GLOAD(kbase);
  G1_LSTORE(0);
  G1_STATS(kbase);
  __syncthreads();

  const int fA = (l15 >> 2) & 3;        // row-swizzle term, mi/w-independent
  const int NS = KH_ / 32;              // 24 K-steps per half
  for (int s = 0; s < NS; ++s) {
    const int cur = s & 1;
    if (s + 1 < NS) G1_GLOAD(kbase + (s + 1) * 32);
    {
      const int browB = w * 16 + l15;
      bf8 bfr = *(const bf8*)&Bs[cur][browB * 32 + (l4 ^ fA) * 8];
#pragma unroll
      for (int mi = 0; mi < 8; ++mi) {
        bf8 afr = *(const bf8*)&As[cur][(mi * 16 + l15) * 32 + (l4 ^ fA) * 8];
        acc[mi] = __builtin_amdgcn_mfma_f32_16x16x32_bf16(afr, bfr, acc[mi], 0, 0, 0);
      }
    }
    if (s + 1 < NS) {
      G1_LSTORE(cur ^ 1);
      G1_STATS(kbase + (s + 1) * 32);
    }
    __syncthreads();
  }

  // store partial acc as fp32 h_pre[khalf][b][t][h]
  const int t = t0 + w * 16 + l15;
  if (t < T_) {
    float* dst = h_pre + (size_t)blockIdx.z * B_ * T_ * H_ + ((size_t)b * T_ + t) * H_;
#pragma unroll
    for (int mi = 0; mi < 8; ++mi)
      *(f4*)&dst[mi * 16 + l4 * 4] = acc[mi];
  }
}

// ---------------- K2: reduce stats partials -> mean0/std0 ---------------------
__global__ __launch_bounds__(256) void k_stats_reduce(
    const float* __restrict__ sp1, const float* __restrict__ sp2,
    const float* __restrict__ mask,
    float* __restrict__ mean0, float* __restrict__ std0) {
  __shared__ float rs[4];
  const int b = blockIdx.x / (C_ / 256);
  const int chunk = blockIdx.x % (C_ / 256);
  const int tid = threadIdx.x;
  const int lane = tid & 63;
  const int wv = tid >> 6;
  // block-wide sum of mask row
  float sm = 0.f;
  for (int i = tid; i < T_; i += 256) sm += mask[(size_t)b * T_ + i];
#pragma unroll
  for (int off = 32; off; off >>= 1) sm += __shfl_xor(sm, off);
  if (lane == 0) rs[wv] = sm;
  __syncthreads();
  sm = rs[0] + rs[1] + rs[2] + rs[3];

  const int c = chunk * 256 + tid;
  float s1 = 0.f, s2 = 0.f;
#pragma unroll 8
  for (int tile = 0; tile < NTL_; ++tile) {
    const size_t j = ((size_t)b * NTL_ + tile) * C_ + c;
    s1 += sp1[j];
    s2 += sp2[j];
  }
  float mean = s1 / sm;
  float var = s2 / sm - mean * mean;
  mean0[b * C_ + c] = mean;
  std0[b * C_ + c] = sqrtf(fmaxf(var, 1e-5f));
}

// ---------------- K3: hconst GEMV + wl1 L1-norms in ONE launch ----------------
__global__ __launch_bounds__(256) void k_hconst_wl1(
    const float* __restrict__ w1, const float* __restrict__ b1,
    const float* __restrict__ mean0, const float* __restrict__ std0,
    const float* __restrict__ w2,
    float* __restrict__ hconst, float* __restrict__ wl1) {
  const int wave = threadIdx.x >> 6;
  const int lane = threadIdx.x & 63;
  if (blockIdx.x < B_ * H_ / 4) {
    const int idx = blockIdx.x * 4 + wave;      // b*H + h
    const int b = idx >> 7;
    const int h = idx & (H_ - 1);
    const float* wm  = w1 + (size_t)h * C3_ + C_;
    const float* wsd = wm + C_;
    const float* mn = mean0 + b * C_;
    const float* sd = std0 + b * C_;
    float s = 0.f;
    for (int c = lane; c < C_; c += 64)
      s += wm[c] * mn[c] + wsd[c] * sd[c];
#pragma unroll
    for (int off = 32; off; off >>= 1) s += __shfl_xor(s, off);
    if (lane == 0) hconst[idx] = s + b1[h];
  } else {
    const int c = (blockIdx.x - B_ * H_ / 4) * 4 + wave;
    const float* wr = w2 + (size_t)c * H_;
    float s = fabsf(wr[lane]) + fabsf(wr[lane + 64]);
#pragma unroll
    for (int off = 32; off; off >>= 1) s += __shfl_xor(s, off);
    if (lane == 0) wl1[c] = s;
  }
}

// ---------------- K4: LN epilogue: h_preA+h_preB+hconst -> relu/LN/tanh -------
// grid (32 t-tiles, B); 256 thr = 64 t x 4 parts; part owns 32 h of one t.
__global__ __launch_bounds__(256) void k_ln_epi(
    const float* __restrict__ h_pre, const float* __restrict__ hconst,
    const float* __restrict__ g1, const float* __restrict__ be1,
    unsigned short* __restrict__ hlnT) {
  const int b = blockIdx.y;
  const int t = blockIdx.x * 64 + (threadIdx.x >> 2);
  const int part = threadIdx.x & 3;
  if (t >= T_) return;
  const float* srcA = h_pre + ((size_t)b * T_ + t) * H_ + part * 32;
  const float* srcB = srcA + (size_t)B_ * T_ * H_;
  const float* hc = hconst + b * H_ + part * 32;
  float v[32];
  float sum = 0.f, ssq = 0.f;
#pragma unroll
  for (int j = 0; j < 8; ++j) {
    float4 hA = *(const float4*)(srcA + j * 4);
    float4 hB = *(const float4*)(srcB + j * 4);
    float4 c4 = *(const float4*)(hc + j * 4);
    const float* pa = (const float*)&hA;
    const float* pb = (const float*)&hB;
    const float* cp = (const float*)&c4;
#pragma unroll
    for (int r = 0; r < 4; ++r) {
      float u = fmaxf(pa[r] + pb[r] + cp[r], 0.f);
      v[j * 4 + r] = u;
      sum += u;
      ssq += u * u;
    }
  }
  // reduce over the 4 parts (consecutive lanes)
  sum += __shfl_xor(sum, 1); sum += __shfl_xor(sum, 2);
  ssq += __shfl_xor(ssq, 1); ssq += __shfl_xor(ssq, 2);
  const float mean = sum * (1.f / 128.f);
  const float rstd = rsqrtf(ssq * (1.f / 128.f) - mean * mean + 1e-5f);
  unsigned short* dst = hlnT + ((size_t)b * T_ + t) * H_ + part * 32;
  const float* gp = g1 + part * 32;
  const float* ep = be1 + part * 32;
#pragma unroll
  for (int m = 0; m < 4; ++m) {
    bf8 p;
#pragma unroll
    for (int r = 0; r < 8; ++r) {
      int j = m * 8 + r;
      p[r] = (short)f2b(tanhf((v[j] - mean) * rstd * gp[j] + ep[j]));
    }
    *(bf8*)&dst[m * 8] = p;
  }
}

// ---------------- K5: MFMA GEMM2 (alpha=w2@hln) + FIXED-MAX softmax + pooling -
// grid (24 c-tiles of 64, B, NT parts); part owns t in [part*512, +512).
// c-tile halved 128->64 vs R10: ~half the per-block VGPR state -> 4-5
// blocks/CU resident (LDS 32KB Hs only), 2x block parallelism, same totals.
// e = exp(alpha - wl1[c]): no running max, no rescale; Mc cancels in s1/s0.
__global__ __launch_bounds__(256) void k_gemm2_pool(
    const float* __restrict__ x, const float* __restrict__ mask,
    const float* __restrict__ w2, const unsigned short* __restrict__ hlnT,
    const float* __restrict__ wl1,
    float* __restrict__ ps0, float* __restrict__ ps1, float* __restrict__ ps2) {
  __shared__ __align__(16) short Hs[2][64 * 128];   // [t][h] swizzled, 2x16KB
  const int b = blockIdx.y;
  const int c0 = blockIdx.x * 64;
  const int part = blockIdx.z;
  const int tb = part * 512;
  const int te = min(tb + 512, T_);
  const int tid = threadIdx.x;
  const int lane = tid & 63;
  const int w = tid >> 6;
  const int l15 = lane & 15;
  const int l4 = lane >> 4;

  // A-frags in registers: af[ks] = w2[c0+w*16+l15][(ks*4+l4)*8 ..+8]
  bf8 af[4];
#pragma unroll
  for (int ks = 0; ks < 4; ++ks) {
    const float* src = w2 + (size_t)(c0 + w * 16 + l15) * H_ + (ks * 4 + l4) * 8;
    float4 v0 = *(const float4*)src;
    float4 v1 = *(const float4*)(src + 4);
    bf8 p;
    p[0] = (short)f2b(v0.x); p[1] = (short)f2b(v0.y);
    p[2] = (short)f2b(v0.z); p[3] = (short)f2b(v0.w);
    p[4] = (short)f2b(v1.x); p[5] = (short)f2b(v1.y);
    p[6] = (short)f2b(v1.z); p[7] = (short)f2b(v1.w);
    af[ks] = p;
  }

  // static per-row logit bound Mc (exp arg <= 0, never overflows)
  float Mc[4];
  {
    float4 m4 = *(const float4*)(wl1 + c0 + w * 16 + l4 * 4);
    Mc[0] = m4.x; Mc[1] = m4.y; Mc[2] = m4.z; Mc[3] = m4.w;
  }

  float s0[4], s1[4], s2[4];
#pragma unroll
  for (int r = 0; r < 4; ++r) { s0[r] = 0.f; s1[r] = 0.f; s2[r] = 0.f; }

  bf8 hreg[4];
#define G2_HLOAD(T0)                                                          \
  {                                                                           \
    _Pragma("unroll")                                                         \
    for (int q = 0; q < 4; ++q) {                                             \
      int idx = q * 256 + tid;                                                \
      int row = idx >> 4, slot = idx & 15;                                    \
      int t = (T0) + row;                                                     \
      if (t > T_ - 1) t = T_ - 1;                                             \
      hreg[q] = *(const bf8*)(hlnT + ((size_t)b * T_ + t) * H_ + slot * 8);   \
    }                                                                         \
  }
#define G2_HSTORE(BUF)                                                        \
  {                                                                           \
    _Pragma("unroll")                                                         \
    for (int q = 0; q < 4; ++q) {                                             \
      int idx = q * 256 + tid;                                                \
      int row = idx >> 4, slot = idx & 15;                                    \
      *(bf8*)&Hs[BUF][row * 128 + (slot ^ (row & 15)) * 8] = hreg[q];         \
    }                                                                         \
  }

  G2_HLOAD(tb);
  G2_HSTORE(0);
  __syncthreads();

  const int NCH = (te - tb + 63) / 64;   // <= 8
  for (int ch = 0; ch < NCH; ++ch) {
    const int t0 = tb + ch * 64;
    const int cur = ch & 1;
    if (ch + 1 < NCH) G2_HLOAD(t0 + 64);

    // issue-early: mask + x loads for this chunk, consumed after MFMA
    float mk[4];
    int tcol[4];
#pragma unroll
    for (int nj = 0; nj < 4; ++nj) {
      int t = t0 + nj * 16 + l15;
      tcol[nj] = (t < T_) ? t : (T_ - 1);
      mk[nj] = (t < T_) ? mask[(size_t)b * T_ + t] : 0.f;
    }
    float xv[4][4];
#pragma unroll
    for (int reg = 0; reg < 4; ++reg) {
      const int c = c0 + w * 16 + l4 * 4 + reg;
      const float* xrow = x + ((size_t)(b * C_ + c)) * T_;
#pragma unroll
      for (int nj = 0; nj < 4; ++nj) xv[reg][nj] = xrow[tcol[nj]];
    }

    f4 acc[4];
#pragma unroll
    for (int nj = 0; nj < 4; ++nj) { f4 z = {0.f, 0.f, 0.f, 0.f}; acc[nj] = z; }

#pragma unroll
    for (int ks = 0; ks < 4; ++ks) {
      const int sw = (ks * 4 + l4) ^ l15;   // row&15 == l15 for B rows
      bf8 bb[4];
#pragma unroll
      for (int nj = 0; nj < 4; ++nj)
        bb[nj] = *(const bf8*)&Hs[cur][(nj * 16 + l15) * 128 + sw * 8];
#pragma unroll
      for (int nj = 0; nj < 4; ++nj)
        acc[nj] = __builtin_amdgcn_mfma_f32_16x16x32_bf16(af[ks], bb[nj], acc[nj], 0, 0, 0);
    }

    // epilogue: fixed-max exp + pooled partial sums (no serial chain)
#pragma unroll
    for (int reg = 0; reg < 4; ++reg) {
      float a0 = s0[reg], a1 = s1[reg], a2 = s2[reg];
#pragma unroll
      for (int nj = 0; nj < 4; ++nj) {
        float e = (mk[nj] != 0.f) ? __expf(acc[nj][reg] - Mc[reg]) : 0.f;
        float xvv = xv[reg][nj];
        a0 += e; a1 += e * xvv; a2 += e * xvv * xvv;
      }
      s0[reg] = a0; s1[reg] = a1; s2[reg] = a2;
    }

    // HSTORE after the epilogue: the epilogue VALU hides this iter's HLOAD
    // latency; buffer cur^1 was drained at the previous iteration's barrier.
    if (ch + 1 < NCH) G2_HSTORE(cur ^ 1);
    __syncthreads();
  }

  // merge the 16 lanes (t-cols) of each row group: plain adds
#pragma unroll
  for (int off = 1; off < 16; off <<= 1) {
#pragma unroll
    for (int r = 0; r < 4; ++r) {
      s0[r] += __shfl_xor(s0[r], off);
      s1[r] += __shfl_xor(s1[r], off);
      s2[r] += __shfl_xor(s2[r], off);
    }
  }
  if (l15 == 0) {
#pragma unroll
    for (int reg = 0; reg < 4; ++reg) {
      const int c = c0 + w * 16 + l4 * 4 + reg;
      const size_t j = ((size_t)(b * NT_ + part)) * C_ + c;
      ps0[j] = s0[reg]; ps1[j] = s1[reg]; ps2[j] = s2[reg];
    }
  }
}

// ---------------- K5b: plain-sum the NT t-part partials -> pooled -------------
__global__ __launch_bounds__(256) void k_pool_merge(
    const float* __restrict__ ps0, const float* __restrict__ ps1,
    const float* __restrict__ ps2, float* __restrict__ pooled) {
  const int idx = blockIdx.x * 256 + threadIdx.x;   // b*C + c
  const int b = idx / C_;
  const int c = idx - b * C_;
  float s0 = 0.f, s1 = 0.f, s2 = 0.f;
#pragma unroll
  for (int p = 0; p < NT_; ++p) {
    const size_t j = ((size_t)(b * NT_ + p)) * C_ + c;
    s0 += ps0[j]; s1 += ps1[j]; s2 += ps2[j];
  }
  float mean = s1 / s0;
  float var = s2 / s0 - mean * mean;
  pooled[b * C2_ + c] = mean;
  pooled[b * C2_ + C_ + c] = sqrtf(fmaxf(var, 1e-5f));
}

// ---------------- K6: final LN over 2C channels per b -------------------------
__global__ __launch_bounds__(256) void k_final_ln(
    const float* __restrict__ pooled, const float* __restrict__ g2,
    const float* __restrict__ be2, float* __restrict__ out) {
  __shared__ float rs[8];
  const int b = blockIdx.x;
  const int tid = threadIdx.x;
  const int lane = tid & 63;
  const int wave = tid >> 6;
  const float* p = pooled + b * C2_;
  float s = 0.f, q = 0.f;
  for (int i = tid; i < C2_; i += 256) {
    float v = p[i];
    s += v;
    q += v * v;
  }
#pragma unroll
  for (int off = 32; off; off >>= 1) {
    s += __shfl_xor(s, off);
    q += __shfl_xor(q, off);
  }
  if (lane == 0) { rs[wave] = s; rs[4 + wave] = q; }
  __syncthreads();
  s = rs[0] + rs[1] + rs[2] + rs[3];
  q = rs[4] + rs[5] + rs[6] + rs[7];
  float mean = s * (1.f / C2_);
  float var = q * (1.f / C2_) - mean * mean;
  float rstd = rsqrtf(var + 1e-5f);
  for (int i = tid; i < C2_; i += 256)
    out[b * C2_ + i] = (p[i] - mean) * rstd * g2[i] + be2[i];
}

extern "C" void kernel_launch(void* const* d_in, const int* in_sizes, int n_in,
                              void* d_out, int out_size, void* d_ws, size_t ws_size,
                              hipStream_t stream) {
  const float* x    = (const float*)d_in[0];
  const float* mask = (const float*)d_in[1];
  const float* w1   = (const float*)d_in[2];
  const float* b1   = (const float*)d_in[3];
  const float* g1   = (const float*)d_in[4];
  const float* be1  = (const float*)d_in[5];
  const float* w2   = (const float*)d_in[6];
  // d_in[7] = b2: per-(b,c) constant on softmax logits -> softmax-invariant, dropped
  const float* g2   = (const float*)d_in[8];
  const float* be2  = (const float*)d_in[9];
  float* out = (float*)d_out;

  float* ws     = (float*)d_ws;
  float* mean0  = ws;                   // B*C
  float* std0   = mean0 + B_ * C_;      // B*C
  float* hconst = std0 + B_ * C_;       // B*H
  float* pooled = hconst + B_ * H_;     // B*2C
  float* wl1    = pooled + B_ * C2_;    // C
  float* ps0    = wl1 + C_;             // B*NT*C each:
  float* ps1    = ps0 + B_ * NT_ * C_;
  float* ps2    = ps1 + B_ * NT_ * C_;
  float* sp1    = ps2 + B_ * NT_ * C_;  // B*NTL*C each:
  float* sp2    = sp1 + B_ * NTL_ * C_;
  float* h_pre  = sp2 + B_ * NTL_ * C_; // 2 x B*T*H fp32 (K-half partials)
  unsigned short* hlnT = (unsigned short*)(h_pre + 2 * (size_t)B_ * T_ * H_);  // B*T*H bf16

  k_gemm1_stats<<<dim3(NTL_, B_, 2), dim3(256), 0, stream>>>(x, w1, mask, h_pre, sp1, sp2);
  k_stats_reduce<<<dim3(B_ * C_ / 256), dim3(256), 0, stream>>>(sp1, sp2, mask, mean0, std0);
  k_hconst_wl1<<<dim3(B_ * H_ / 4 + C_ / 4), dim3(256), 0, stream>>>(
      w1, b1, mean0, std0, w2, hconst, wl1);
  k_ln_epi<<<dim3(NTL_, B_), dim3(256), 0, stream>>>(h_pre, hconst, g1, be1, hlnT);
  k_gemm2_pool<<<dim3(C_ / 64, B_, NT_), dim3(256), 0, stream>>>(x, mask, w2, hlnT, wl1,
                                                                 ps0, ps1, ps2);
  k_pool_merge<<<dim3(B_ * C_ / 256), dim3(256), 0, stream>>>(ps0, ps1, ps2, pooled);
  k_final_ln<<<dim3(B_), dim3(256), 0, stream>>>(pooled, g2, be2, out);
}